// Round 8
// baseline (705.623 us; speedup 1.0000x reference)
//
#include <hip/hip_runtime.h>
#include <hip/hip_bf16.h>
#include <stdint.h>

#define IN_F 768
#define HID 256
#define OUTF 128

typedef short bf16x8 __attribute__((ext_vector_type(8)));
typedef float f32x4 __attribute__((ext_vector_type(4)));

__device__ inline short f2bf(float f) {
  union { __hip_bfloat16 b; short s; } u;
  u.b = __float2bfloat16(f);
  return u.s;
}
__device__ inline float bf2f(uint32_t bits) {
  union { uint32_t u; float f; } x; x.u = bits << 16; return x.f;
}

// ---------------- prep: zero counters + transpose/convert both weights ----
__global__ void k_prep(const float* __restrict__ W1, short* __restrict__ W1t,
                       const float* __restrict__ W2, short* __restrict__ W2t,
                       int* __restrict__ cnt, int nz) {
  int idx = blockIdx.x * blockDim.x + threadIdx.x;
  const int n1 = IN_F * HID;
  const int n2 = HID * OUTF;
  if (idx < n1) {
    int nn = idx / IN_F, kk = idx - nn * IN_F;
    W1t[idx] = f2bf(W1[kk * HID + nn]);
  } else if (idx < n1 + n2) {
    int j = idx - n1;
    int nn = j / HID, kk = j - nn * HID;
    W2t[j] = f2bf(W2[kk * OUTF + nn]);
  } else {
    int z = idx - n1 - n2;
    if (z < nz) cnt[z] = 0;
  }
}

__global__ void k_hist(const int* __restrict__ dst, int* __restrict__ cnt, int e) {
  int i = blockIdx.x * blockDim.x + threadIdx.x;
  if (i < e) atomicAdd(&cnt[dst[i]], 1);
}

// scan-free CSR row allocation: wave-local shuffle scan + 1 atomic per wave.
__global__ void k_alloc(const int* __restrict__ cnt, int* __restrict__ rowp,
                        int* __restrict__ cursor, float* __restrict__ dinv,
                        int* __restrict__ gtot, int n) {
  int i = blockIdx.x * blockDim.x + threadIdx.x;
  int lane = threadIdx.x & 63;
  int v = (i < n) ? cnt[i] : 0;
  int incl = v;
#pragma unroll
  for (int off = 1; off < 64; off <<= 1) {
    int t = __shfl_up(incl, off);
    if (lane >= off) incl += t;
  }
  int wsum = __shfl(incl, 63);
  int base = 0;
  if (lane == 63) base = atomicAdd(gtot, wsum);
  base = __shfl(base, 63);
  if (i < n) {
    int start = base + incl - v;
    rowp[i] = start;
    cursor[i] = start;
    dinv[i] = rsqrtf((float)(v + 1));  // +1 self-loop
  }
}

__global__ void k_fill(const int* __restrict__ src, const int* __restrict__ dst,
                       int* __restrict__ cursor, int* __restrict__ ssrc, int e) {
  int i = blockIdx.x * blockDim.x + threadIdx.x;
  if (i < e) {
    int d = dst[i];
    int pos = atomicAdd(&cursor[d], 1);
    ssrc[pos] = src[i];
  }
}

// ---------------- GEMM1 (rep-instrumented this round) ---------------------
__global__ __launch_bounds__(256, 2) void k_gemm1(const float* __restrict__ A,
                                                  const short* __restrict__ Bt,
                                                  short* __restrict__ C,
                                                  const float* __restrict__ dinv,
                                                  int M, int K, int rep) {
  __shared__ __align__(16) short As[128 * 32];
  __shared__ __align__(16) short Bs[256 * 32];
  const int tid = threadIdx.x;
  const int tile_m = blockIdx.x * 128;
  const int wave = tid >> 6;
  const int lane = tid & 63;
  const int wm = (wave & 1) * 64;
  const int wn = (wave >> 1) * 128;
  const int lrow = lane & 15;
  const int quad = lane >> 4;

  const int rA0 = tid >> 2;
  const int colA = (tid & 3) * 8;
  const int rA1 = rA0 + 64;
  int gr0 = tile_m + rA0; if (gr0 >= M) gr0 = M - 1;
  int gr1 = tile_m + rA1; if (gr1 >= M) gr1 = M - 1;
  const float* pA0 = A + (size_t)gr0 * K + colA;
  const float* pA1 = A + (size_t)gr1 * K + colA;
  const short* pB = Bt + (size_t)rA0 * K + colA;

  for (int rr = 0; rr < rep; ++rr) {
    float4 a0[2], a1[2];
    bf16x8 bgl[4];
    auto ldglb = [&](int k0) {
      a0[0] = *(const float4*)(pA0 + k0);
      a0[1] = *(const float4*)(pA0 + k0 + 4);
      a1[0] = *(const float4*)(pA1 + k0);
      a1[1] = *(const float4*)(pA1 + k0 + 4);
#pragma unroll
      for (int q = 0; q < 4; q++)
        bgl[q] = *(const bf16x8*)(pB + (size_t)(q * 64) * K + k0);
    };

    f32x4 zero = {0.f, 0.f, 0.f, 0.f};
    f32x4 acc[4][8];
#pragma unroll
    for (int i = 0; i < 4; i++)
#pragma unroll
      for (int j = 0; j < 8; j++) acc[i][j] = zero;

    ldglb(0);
    for (int k0 = 0; k0 < K; k0 += 32) {
      bf16x8 pk0, pk1;
      pk0[0] = f2bf(a0[0].x); pk0[1] = f2bf(a0[0].y); pk0[2] = f2bf(a0[0].z); pk0[3] = f2bf(a0[0].w);
      pk0[4] = f2bf(a0[1].x); pk0[5] = f2bf(a0[1].y); pk0[6] = f2bf(a0[1].z); pk0[7] = f2bf(a0[1].w);
      pk1[0] = f2bf(a1[0].x); pk1[1] = f2bf(a1[0].y); pk1[2] = f2bf(a1[0].z); pk1[3] = f2bf(a1[0].w);
      pk1[4] = f2bf(a1[1].x); pk1[5] = f2bf(a1[1].y); pk1[6] = f2bf(a1[1].z); pk1[7] = f2bf(a1[1].w);
      *(bf16x8*)&As[tid * 8] = pk0;
      *(bf16x8*)&As[(tid + 256) * 8] = pk1;
#pragma unroll
      for (int q = 0; q < 4; q++) *(bf16x8*)&Bs[(tid + q * 256) * 8] = bgl[q];
      __syncthreads();

      if (k0 + 32 < K) ldglb(k0 + 32);

      bf16x8 af[4], bfr[8];
#pragma unroll
      for (int i = 0; i < 4; i++)
        af[i] = *(const bf16x8*)&As[(wm + i * 16 + lrow) * 32 + quad * 8];
#pragma unroll
      for (int j = 0; j < 8; j++)
        bfr[j] = *(const bf16x8*)&Bs[(wn + j * 16 + lrow) * 32 + quad * 8];
#pragma unroll
      for (int i = 0; i < 4; i++)
#pragma unroll
        for (int j = 0; j < 8; j++)
          acc[i][j] = __builtin_amdgcn_mfma_f32_16x16x32_bf16(af[i], bfr[j],
                                                              acc[i][j], 0, 0, 0);
      __syncthreads();
    }

#pragma unroll
    for (int i = 0; i < 4; i++) {
#pragma unroll
      for (int r = 0; r < 4; r++) {
        int grow = tile_m + wm + i * 16 + quad * 4 + r;
        if (grow < M) {
          float dv = dinv[grow];
#pragma unroll
          for (int j = 0; j < 8; j++) {
            int gcol = wn + j * 16 + lrow;
            C[(size_t)grow * HID + gcol] = f2bf(dv * acc[i][j][r]);
          }
        }
      }
    }
  }
}

// ---------------- async MFMA GEMM (rep-instrumented this round) -----------
__device__ inline void glds16(const short* g, short* l) {
  __builtin_amdgcn_global_load_lds((const __attribute__((address_space(1))) void*)g,
                                   (__attribute__((address_space(3))) void*)l, 16, 0, 0);
}

__global__ __launch_bounds__(256) void k_gemm_a(const short* __restrict__ A,
                                                const short* __restrict__ Bt,
                                                short* __restrict__ C,
                                                const float* __restrict__ dinv,
                                                int M, int N, int K, int rep) {
  __shared__ __align__(16) short As[128 * 32];
  __shared__ __align__(16) short Bs[128 * 32];
  const int tid = threadIdx.x;
  const int tile_m = blockIdx.x * 128;
  const int tile_n = blockIdx.y * 128;
  const int wave = tid >> 6;
  const int lane = tid & 63;
  const int wm = (wave & 1) * 64;
  const int wn = (wave >> 1) * 64;
  const int lrow = lane & 15;
  const int quad = lane >> 4;

  const int c = tid, c2 = tid + 256;
  const int rowA = c >> 2, colA = (c & 3) * 8;
  const int rowA2 = c2 >> 2, colA2 = (c2 & 3) * 8;
  int grA = tile_m + rowA;  if (grA >= M) grA = M - 1;
  int grA2 = tile_m + rowA2; if (grA2 >= M) grA2 = M - 1;
  const short* pA = A + (size_t)grA * K + colA;
  const short* pA2 = A + (size_t)grA2 * K + colA2;
  const short* pB = Bt + (size_t)(tile_n + rowA) * K + colA;
  const short* pB2 = Bt + (size_t)(tile_n + rowA2) * K + colA2;

  for (int rr = 0; rr < rep; ++rr) {
    f32x4 zero = {0.f, 0.f, 0.f, 0.f};
    f32x4 acc[4][4];
#pragma unroll
    for (int i = 0; i < 4; i++)
#pragma unroll
      for (int j = 0; j < 4; j++) acc[i][j] = zero;

    for (int k0 = 0; k0 < K; k0 += 32) {
      glds16(pA + k0, &As[c * 8]);
      glds16(pA2 + k0, &As[c2 * 8]);
      glds16(pB + k0, &Bs[c * 8]);
      glds16(pB2 + k0, &Bs[c2 * 8]);
      __builtin_amdgcn_s_waitcnt(0xcf70);  // vmcnt(0)
      __syncthreads();

      bf16x8 af[4], bfr[4];
#pragma unroll
      for (int i = 0; i < 4; i++)
        af[i] = *(const bf16x8*)&As[(wm + i * 16 + lrow) * 32 + quad * 8];
#pragma unroll
      for (int j = 0; j < 4; j++)
        bfr[j] = *(const bf16x8*)&Bs[(wn + j * 16 + lrow) * 32 + quad * 8];
#pragma unroll
      for (int i = 0; i < 4; i++)
#pragma unroll
        for (int j = 0; j < 4; j++)
          acc[i][j] = __builtin_amdgcn_mfma_f32_16x16x32_bf16(af[i], bfr[j],
                                                              acc[i][j], 0, 0, 0);
      __syncthreads();
    }

#pragma unroll
    for (int i = 0; i < 4; i++) {
#pragma unroll
      for (int r = 0; r < 4; r++) {
        int grow = tile_m + wm + i * 16 + quad * 4 + r;
        if (grow < M) {
          float dv = dinv[grow];
#pragma unroll
          for (int j = 0; j < 4; j++) {
            int gcol = tile_n + wn + j * 16 + lrow;
            C[(size_t)grow * N + gcol] = f2bf(dv * acc[i][j][r]);
          }
        }
      }
    }
  }
}

// ---------------- CSR aggregation (rep-instrumented this round) -----------
template <int F, bool RELU, typename OT>
__global__ __launch_bounds__(256) void k_agg5(const short* __restrict__ H,
                                              const int* __restrict__ rowp,
                                              const int* __restrict__ cnt,
                                              const int* __restrict__ ssrc,
                                              const float* __restrict__ dinv,
                                              const float* __restrict__ bias,
                                              OT* __restrict__ out, int n, int rep) {
  constexpr int LPE = F / 8;     // lanes per edge-row: 32 (F=256), 16 (F=128)
  constexpr int EPW = 64 / LPE;  // edges per wave-load: 2 or 4
  const int lane = threadIdx.x & 63;
  const int i = blockIdx.x * 4 + (threadIdx.x >> 6);
  if (i >= n) return;
  const int q = lane / LPE;        // edge sub-group
  const int fl = (lane % LPE) * 8; // feat offset (8 feats = 16 B bf16)
  const float di = dinv[i];

  for (int rr = 0; rr < rep; ++rr) {
    float a[8], b[8];
    auto fmadd = [&](float* ac, uint4 u, float w) {
      ac[0] = fmaf(w, bf2f(u.x & 0xffffu), ac[0]);
      ac[1] = fmaf(w, bf2f(u.x >> 16), ac[1]);
      ac[2] = fmaf(w, bf2f(u.y & 0xffffu), ac[2]);
      ac[3] = fmaf(w, bf2f(u.y >> 16), ac[3]);
      ac[4] = fmaf(w, bf2f(u.z & 0xffffu), ac[4]);
      ac[5] = fmaf(w, bf2f(u.z >> 16), ac[5]);
      ac[6] = fmaf(w, bf2f(u.w & 0xffffu), ac[6]);
      ac[7] = fmaf(w, bf2f(u.w >> 16), ac[7]);
    };

    {  // self term (pre-scaled row), owned by sub-group 0 only
      uint4 u = *(const uint4*)(H + (size_t)i * F + fl);
#pragma unroll
      for (int j = 0; j < 8; j++) { a[j] = 0.f; b[j] = 0.f; }
      fmadd(a, u, (q == 0) ? 1.f : 0.f);
    }

    const int p0 = rowp[i];
    const int deg = cnt[i];
    for (int pb = 0; pb < deg; pb += 64) {
      int m = deg - pb; if (m > 64) m = 64;
      int sl = (lane < m) ? ssrc[p0 + pb + lane] : 0;
      for (int e = 0; e < m; e += 2 * EPW) {
        const int i0 = e + q, i1 = e + EPW + q;
        const int s0 = __shfl(sl, i0);
        const int s1 = __shfl(sl, i1);
        const float w0 = (i0 < m) ? 1.f : 0.f;
        const float w1 = (i1 < m) ? 1.f : 0.f;
        uint4 u0 = *(const uint4*)(H + (size_t)s0 * F + fl);
        uint4 u1 = *(const uint4*)(H + (size_t)s1 * F + fl);
        fmadd(a, u0, w0);
        fmadd(b, u1, w1);
      }
    }
#pragma unroll
    for (int j = 0; j < 8; j++) a[j] += b[j];
#pragma unroll
    for (int mask = LPE; mask < 64; mask <<= 1) {
#pragma unroll
      for (int j = 0; j < 8; j++) a[j] += __shfl_xor(a[j], mask);
    }

    if (q == 0) {
      float o[8];
#pragma unroll
      for (int j = 0; j < 8; j++) {
        o[j] = di * a[j] + bias[fl + j];
        if (RELU) o[j] = fmaxf(o[j], 0.f);
      }
      if constexpr (sizeof(OT) == 2) {
        uint4 pk;
        pk.x = (uint32_t)(uint16_t)f2bf(o[0]) | ((uint32_t)(uint16_t)f2bf(o[1]) << 16);
        pk.y = (uint32_t)(uint16_t)f2bf(o[2]) | ((uint32_t)(uint16_t)f2bf(o[3]) << 16);
        pk.z = (uint32_t)(uint16_t)f2bf(o[4]) | ((uint32_t)(uint16_t)f2bf(o[5]) << 16);
        pk.w = (uint32_t)(uint16_t)f2bf(o[6]) | ((uint32_t)(uint16_t)f2bf(o[7]) << 16);
        *(uint4*)((short*)out + (size_t)i * F + fl) = pk;
      } else {
        float* po = (float*)out + (size_t)i * F + fl;
        *(float4*)po = make_float4(o[0], o[1], o[2], o[3]);
        *(float4*)(po + 4) = make_float4(o[4], o[5], o[6], o[7]);
      }
    }
  }
}

// ---------------- launch ----------------
extern "C" void kernel_launch(void* const* d_in, const int* in_sizes, int n_in,
                              void* d_out, int out_size, void* d_ws, size_t ws_size,
                              hipStream_t stream) {
  const float* x = (const float*)d_in[0];
  const int* ei = (const int*)d_in[1];
  const float* W1 = (const float*)d_in[2];
  const float* b1 = (const float*)d_in[3];
  const float* W2 = (const float*)d_in[4];
  const float* b2 = (const float*)d_in[5];
  float* out = (float*)d_out;

  const int n = in_sizes[0] / IN_F;   // 50000
  const int e = in_sizes[1] / 2;      // 800000
  const int* e_src = ei;
  const int* e_dst = ei + e;

  uint8_t* ws = (uint8_t*)d_ws;
  size_t off = 0;
  auto carve = [&](size_t bytes) {
    uint8_t* p = ws + off;
    off = (off + bytes + 255) & ~(size_t)255;
    return p;
  };
  short* h1 = (short*)carve((size_t)n * HID * 2);
  short* h2 = (short*)carve((size_t)n * HID * 2);
  short* t2 = (short*)carve((size_t)n * OUTF * 2);
  short* w1t = (short*)carve((size_t)HID * IN_F * 2);
  short* w2t = (short*)carve((size_t)OUTF * HID * 2);
  int* cnt = (int*)carve((size_t)(n + 1) * 4);  // cnt[n] = global alloc counter
  int* rowp = (int*)carve((size_t)(n + 1) * 4);
  int* cursor = (int*)carve((size_t)n * 4);
  float* dinv = (float*)carve((size_t)n * 4);
  int* ssrc = (int*)carve((size_t)e * 4);
  (void)n_in; (void)out_size; (void)ws_size;

  // INSTRUMENTATION ROUND: rep=3 on the 4 main kernels (idempotent redo) so
  // they exceed the ~92us harness-fill cutoff and appear in rocprof top-5.
  // True duration = shown/3; sum(mains) = (dur_us - 446)/2. Revert next round.
  const int REP = 3;

  // prep: both weight transposes + zero cnt[n+1] in one launch
  {
    int total = IN_F * HID + HID * OUTF + (n + 1);
    k_prep<<<(total + 255) / 256, 256, 0, stream>>>(W1, w1t, W2, w2t, cnt, n + 1);
  }

  // CSR build
  k_hist<<<(e + 255) / 256, 256, 0, stream>>>(e_dst, cnt, e);
  k_alloc<<<(n + 255) / 256, 256, 0, stream>>>(cnt, rowp, cursor, dinv, &cnt[n], n);
  k_fill<<<(e + 255) / 256, 256, 0, stream>>>(e_src, e_dst, cursor, ssrc, e);

  // layer 1: h1 = dinv .* (x @ W1); h2 = relu(dinv .* (sum + self) + b1)
  k_gemm1<<<(n + 127) / 128, 256, 0, stream>>>(x, w1t, h1, dinv, n, IN_F, REP);
  k_agg5<HID, true, short><<<(n + 3) / 4, 256, 0, stream>>>(h1, rowp, cnt, ssrc, dinv, b1, h2, n, REP);

  // layer 2: t2 = dinv .* (h2 @ W2); out = dinv .* (sum + self) + b2
  {
    dim3 grid((n + 127) / 128, OUTF / 128);
    k_gemm_a<<<grid, 256, 0, stream>>>(h2, w2t, t2, dinv, n, OUTF, HID, REP);
  }
  k_agg5<OUTF, false, float><<<(n + 3) / 4, 256, 0, stream>>>(t2, rowp, cnt, ssrc, dinv, b2, out, n, REP);
}

// Round 9
// 467.311 us; speedup vs baseline: 1.5100x; 1.5100x over previous
//
#include <hip/hip_runtime.h>
#include <hip/hip_bf16.h>
#include <stdint.h>

#define IN_F 768
#define HID 256
#define OUTF 128

typedef short bf16x8 __attribute__((ext_vector_type(8)));
typedef float f32x4 __attribute__((ext_vector_type(4)));

__device__ inline short f2bf(float f) {
  union { __hip_bfloat16 b; short s; } u;
  u.b = __float2bfloat16(f);
  return u.s;
}
__device__ inline float bf2f(uint32_t bits) {
  union { uint32_t u; float f; } x; x.u = bits << 16; return x.f;
}

// ---------------- prep: zero counters + transpose/convert both weights ----
__global__ void k_prep(const float* __restrict__ W1, short* __restrict__ W1t,
                       const float* __restrict__ W2, short* __restrict__ W2t,
                       int* __restrict__ cnt, int nz) {
  int idx = blockIdx.x * blockDim.x + threadIdx.x;
  const int n1 = IN_F * HID;
  const int n2 = HID * OUTF;
  if (idx < n1) {
    int nn = idx / IN_F, kk = idx - nn * IN_F;
    W1t[idx] = f2bf(W1[kk * HID + nn]);
  } else if (idx < n1 + n2) {
    int j = idx - n1;
    int nn = j / HID, kk = j - nn * HID;
    W2t[j] = f2bf(W2[kk * OUTF + nn]);
  } else {
    int z = idx - n1 - n2;
    if (z < nz) cnt[z] = 0;
  }
}

__global__ void k_hist(const int* __restrict__ dst, int* __restrict__ cnt, int e) {
  int i = blockIdx.x * blockDim.x + threadIdx.x;
  if (i < e) atomicAdd(&cnt[dst[i]], 1);
}

// scan-free CSR row allocation: wave-local shuffle scan + 1 atomic per wave.
__global__ void k_alloc(const int* __restrict__ cnt, int* __restrict__ rowp,
                        int* __restrict__ cursor, float* __restrict__ dinv,
                        int* __restrict__ gtot, int n) {
  int i = blockIdx.x * blockDim.x + threadIdx.x;
  int lane = threadIdx.x & 63;
  int v = (i < n) ? cnt[i] : 0;
  int incl = v;
#pragma unroll
  for (int off = 1; off < 64; off <<= 1) {
    int t = __shfl_up(incl, off);
    if (lane >= off) incl += t;
  }
  int wsum = __shfl(incl, 63);
  int base = 0;
  if (lane == 63) base = atomicAdd(gtot, wsum);
  base = __shfl(base, 63);
  if (i < n) {
    int start = base + incl - v;
    rowp[i] = start;
    cursor[i] = start;
    dinv[i] = rsqrtf((float)(v + 1));  // +1 self-loop
  }
}

__global__ void k_fill(const int* __restrict__ src, const int* __restrict__ dst,
                       int* __restrict__ cursor, int* __restrict__ ssrc, int e) {
  int i = blockIdx.x * blockDim.x + threadIdx.x;
  if (i < e) {
    int d = dst[i];
    int pos = atomicAdd(&cursor[d], 1);
    ssrc[pos] = src[i];
  }
}

// ---------------- GEMM1 v2: 128x128 tile, grid (M/128, 2), swizzled LDS ---
// r8 counters showed v1 (128x256, grid=391) latency-bound: MfmaUtil 12%,
// Occupancy 16% (1.5 waves/SIMD grid-starved), 1.8M LDS bank conflicts.
// v2: 2x blocks -> ~3 blocks/CU (12 waves), XOR-swizzle kills the 8-way
// read conflict. Swizzle applied on BOTH ds_write and ds_read (reg-staged).
__device__ inline int soff(int row, int q) {  // short-offset into [128][32] tile
  return row * 32 + ((q ^ ((row >> 1) & 3)) << 3);
}

__global__ __launch_bounds__(256, 3) void k_gemm1(const float* __restrict__ A,
                                                  const short* __restrict__ Bt,
                                                  short* __restrict__ C,
                                                  const float* __restrict__ dinv,
                                                  int M, int K) {
  __shared__ __align__(16) short As[128 * 32];
  __shared__ __align__(16) short Bs[128 * 32];
  const int tid = threadIdx.x;
  const int tile_m = blockIdx.x * 128;
  const int tile_n = blockIdx.y * 128;
  const int wave = tid >> 6;
  const int lane = tid & 63;
  const int wm = (wave & 1) * 64;
  const int wn = (wave >> 1) * 64;
  const int lrow = lane & 15;
  const int quad = lane >> 4;

  // staging: chunks c = tid (rows 0..63), c+256 (rows 64..127); 8 elems each
  const int rA0 = tid >> 2;
  const int qA = tid & 3;
  const int colA = qA * 8;
  const int rA1 = rA0 + 64;
  int gr0 = tile_m + rA0; if (gr0 >= M) gr0 = M - 1;
  int gr1 = tile_m + rA1; if (gr1 >= M) gr1 = M - 1;
  const float* pA0 = A + (size_t)gr0 * K + colA;
  const float* pA1 = A + (size_t)gr1 * K + colA;
  const short* pB0 = Bt + (size_t)(tile_n + rA0) * K + colA;
  const short* pB1 = Bt + (size_t)(tile_n + rA1) * K + colA;

  float4 a0[2], a1[2];
  bf16x8 bgl[2];
  auto ldglb = [&](int k0) {
    a0[0] = *(const float4*)(pA0 + k0);
    a0[1] = *(const float4*)(pA0 + k0 + 4);
    a1[0] = *(const float4*)(pA1 + k0);
    a1[1] = *(const float4*)(pA1 + k0 + 4);
    bgl[0] = *(const bf16x8*)(pB0 + k0);
    bgl[1] = *(const bf16x8*)(pB1 + k0);
  };

  f32x4 zero = {0.f, 0.f, 0.f, 0.f};
  f32x4 acc[4][4];
#pragma unroll
  for (int i = 0; i < 4; i++)
#pragma unroll
    for (int j = 0; j < 4; j++) acc[i][j] = zero;

  ldglb(0);
  for (int k0 = 0; k0 < K; k0 += 32) {
    bf16x8 pk0, pk1;
    pk0[0] = f2bf(a0[0].x); pk0[1] = f2bf(a0[0].y); pk0[2] = f2bf(a0[0].z); pk0[3] = f2bf(a0[0].w);
    pk0[4] = f2bf(a0[1].x); pk0[5] = f2bf(a0[1].y); pk0[6] = f2bf(a0[1].z); pk0[7] = f2bf(a0[1].w);
    pk1[0] = f2bf(a1[0].x); pk1[1] = f2bf(a1[0].y); pk1[2] = f2bf(a1[0].z); pk1[3] = f2bf(a1[0].w);
    pk1[4] = f2bf(a1[1].x); pk1[5] = f2bf(a1[1].y); pk1[6] = f2bf(a1[1].z); pk1[7] = f2bf(a1[1].w);
    *(bf16x8*)&As[soff(rA0, qA)] = pk0;
    *(bf16x8*)&As[soff(rA1, qA)] = pk1;
    *(bf16x8*)&Bs[soff(rA0, qA)] = bgl[0];
    *(bf16x8*)&Bs[soff(rA1, qA)] = bgl[1];
    __syncthreads();

    if (k0 + 32 < K) ldglb(k0 + 32);

    bf16x8 af[4], bfr[4];
#pragma unroll
    for (int i = 0; i < 4; i++)
      af[i] = *(const bf16x8*)&As[soff(wm + i * 16 + lrow, quad)];
#pragma unroll
    for (int j = 0; j < 4; j++)
      bfr[j] = *(const bf16x8*)&Bs[soff(wn + j * 16 + lrow, quad)];
#pragma unroll
    for (int i = 0; i < 4; i++)
#pragma unroll
      for (int j = 0; j < 4; j++)
        acc[i][j] = __builtin_amdgcn_mfma_f32_16x16x32_bf16(af[i], bfr[j],
                                                            acc[i][j], 0, 0, 0);
    __syncthreads();
  }

#pragma unroll
  for (int i = 0; i < 4; i++) {
#pragma unroll
    for (int r = 0; r < 4; r++) {
      int grow = tile_m + wm + i * 16 + quad * 4 + r;
      if (grow < M) {
        float dv = dinv[grow];
#pragma unroll
        for (int j = 0; j < 4; j++) {
          int gcol = tile_n + wn + j * 16 + lrow;
          C[(size_t)grow * HID + gcol] = f2bf(dv * acc[i][j][r]);
        }
      }
    }
  }
}

// ---------------- async MFMA GEMM (m97 structure), bf16 A, dinv epilogue --
__device__ inline void glds16(const short* g, short* l) {
  __builtin_amdgcn_global_load_lds((const __attribute__((address_space(1))) void*)g,
                                   (__attribute__((address_space(3))) void*)l, 16, 0, 0);
}

__global__ __launch_bounds__(256) void k_gemm_a(const short* __restrict__ A,
                                                const short* __restrict__ Bt,
                                                short* __restrict__ C,
                                                const float* __restrict__ dinv,
                                                int M, int N, int K) {
  __shared__ __align__(16) short As[128 * 32];
  __shared__ __align__(16) short Bs[128 * 32];
  const int tid = threadIdx.x;
  const int tile_m = blockIdx.x * 128;
  const int tile_n = blockIdx.y * 128;
  const int wave = tid >> 6;
  const int lane = tid & 63;
  const int wm = (wave & 1) * 64;
  const int wn = (wave >> 1) * 64;
  const int lrow = lane & 15;
  const int quad = lane >> 4;

  const int c = tid, c2 = tid + 256;
  const int rowA = c >> 2, colA = (c & 3) * 8;
  const int rowA2 = c2 >> 2, colA2 = (c2 & 3) * 8;
  int grA = tile_m + rowA;  if (grA >= M) grA = M - 1;
  int grA2 = tile_m + rowA2; if (grA2 >= M) grA2 = M - 1;
  const short* pA = A + (size_t)grA * K + colA;
  const short* pA2 = A + (size_t)grA2 * K + colA2;
  const short* pB = Bt + (size_t)(tile_n + rowA) * K + colA;
  const short* pB2 = Bt + (size_t)(tile_n + rowA2) * K + colA2;

  f32x4 zero = {0.f, 0.f, 0.f, 0.f};
  f32x4 acc[4][4];
#pragma unroll
  for (int i = 0; i < 4; i++)
#pragma unroll
    for (int j = 0; j < 4; j++) acc[i][j] = zero;

  for (int k0 = 0; k0 < K; k0 += 32) {
    glds16(pA + k0, &As[c * 8]);
    glds16(pA2 + k0, &As[c2 * 8]);
    glds16(pB + k0, &Bs[c * 8]);
    glds16(pB2 + k0, &Bs[c2 * 8]);
    __builtin_amdgcn_s_waitcnt(0xcf70);  // vmcnt(0)
    __syncthreads();

    bf16x8 af[4], bfr[4];
#pragma unroll
    for (int i = 0; i < 4; i++)
      af[i] = *(const bf16x8*)&As[(wm + i * 16 + lrow) * 32 + quad * 8];
#pragma unroll
    for (int j = 0; j < 4; j++)
      bfr[j] = *(const bf16x8*)&Bs[(wn + j * 16 + lrow) * 32 + quad * 8];
#pragma unroll
    for (int i = 0; i < 4; i++)
#pragma unroll
      for (int j = 0; j < 4; j++)
        acc[i][j] = __builtin_amdgcn_mfma_f32_16x16x32_bf16(af[i], bfr[j],
                                                            acc[i][j], 0, 0, 0);
    __syncthreads();
  }

#pragma unroll
  for (int i = 0; i < 4; i++) {
#pragma unroll
    for (int r = 0; r < 4; r++) {
      int grow = tile_m + wm + i * 16 + quad * 4 + r;
      if (grow < M) {
        float dv = dinv[grow];
#pragma unroll
        for (int j = 0; j < 4; j++) {
          int gcol = tile_n + wn + j * 16 + lrow;
          C[(size_t)grow * N + gcol] = f2bf(dv * acc[i][j][r]);
        }
      }
    }
  }
}

// ---------------- CSR aggregation: wave/node, unweighted sum of pre-scaled
// rows. 16 B/lane gathers; 2-deep accumulator unroll.
template <int F, bool RELU, typename OT>
__global__ __launch_bounds__(256) void k_agg5(const short* __restrict__ H,
                                              const int* __restrict__ rowp,
                                              const int* __restrict__ cnt,
                                              const int* __restrict__ ssrc,
                                              const float* __restrict__ dinv,
                                              const float* __restrict__ bias,
                                              OT* __restrict__ out, int n) {
  constexpr int LPE = F / 8;     // lanes per edge-row: 32 (F=256), 16 (F=128)
  constexpr int EPW = 64 / LPE;  // edges per wave-load: 2 or 4
  const int lane = threadIdx.x & 63;
  const int i = blockIdx.x * 4 + (threadIdx.x >> 6);
  if (i >= n) return;
  const int q = lane / LPE;        // edge sub-group
  const int fl = (lane % LPE) * 8; // feat offset (8 feats = 16 B bf16)
  const float di = dinv[i];

  float a[8], b[8];
  auto fmadd = [&](float* ac, uint4 u, float w) {
    ac[0] = fmaf(w, bf2f(u.x & 0xffffu), ac[0]);
    ac[1] = fmaf(w, bf2f(u.x >> 16), ac[1]);
    ac[2] = fmaf(w, bf2f(u.y & 0xffffu), ac[2]);
    ac[3] = fmaf(w, bf2f(u.y >> 16), ac[3]);
    ac[4] = fmaf(w, bf2f(u.z & 0xffffu), ac[4]);
    ac[5] = fmaf(w, bf2f(u.z >> 16), ac[5]);
    ac[6] = fmaf(w, bf2f(u.w & 0xffffu), ac[6]);
    ac[7] = fmaf(w, bf2f(u.w >> 16), ac[7]);
  };

  {  // self term (pre-scaled row), owned by sub-group 0 only
    uint4 u = *(const uint4*)(H + (size_t)i * F + fl);
#pragma unroll
    for (int j = 0; j < 8; j++) { a[j] = 0.f; b[j] = 0.f; }
    fmadd(a, u, (q == 0) ? 1.f : 0.f);
  }

  const int p0 = rowp[i];
  const int deg = cnt[i];
  for (int pb = 0; pb < deg; pb += 64) {
    int m = deg - pb; if (m > 64) m = 64;
    int sl = (lane < m) ? ssrc[p0 + pb + lane] : 0;
    for (int e = 0; e < m; e += 2 * EPW) {
      const int i0 = e + q, i1 = e + EPW + q;
      const int s0 = __shfl(sl, i0);
      const int s1 = __shfl(sl, i1);
      const float w0 = (i0 < m) ? 1.f : 0.f;
      const float w1 = (i1 < m) ? 1.f : 0.f;
      uint4 u0 = *(const uint4*)(H + (size_t)s0 * F + fl);
      uint4 u1 = *(const uint4*)(H + (size_t)s1 * F + fl);
      fmadd(a, u0, w0);
      fmadd(b, u1, w1);
    }
  }
#pragma unroll
  for (int j = 0; j < 8; j++) a[j] += b[j];
#pragma unroll
  for (int mask = LPE; mask < 64; mask <<= 1) {
#pragma unroll
    for (int j = 0; j < 8; j++) a[j] += __shfl_xor(a[j], mask);
  }

  if (q == 0) {
    float o[8];
#pragma unroll
    for (int j = 0; j < 8; j++) {
      o[j] = di * a[j] + bias[fl + j];
      if (RELU) o[j] = fmaxf(o[j], 0.f);
    }
    if constexpr (sizeof(OT) == 2) {
      uint4 pk;
      pk.x = (uint32_t)(uint16_t)f2bf(o[0]) | ((uint32_t)(uint16_t)f2bf(o[1]) << 16);
      pk.y = (uint32_t)(uint16_t)f2bf(o[2]) | ((uint32_t)(uint16_t)f2bf(o[3]) << 16);
      pk.z = (uint32_t)(uint16_t)f2bf(o[4]) | ((uint32_t)(uint16_t)f2bf(o[5]) << 16);
      pk.w = (uint32_t)(uint16_t)f2bf(o[6]) | ((uint32_t)(uint16_t)f2bf(o[7]) << 16);
      *(uint4*)((short*)out + (size_t)i * F + fl) = pk;
    } else {
      float* po = (float*)out + (size_t)i * F + fl;
      *(float4*)po = make_float4(o[0], o[1], o[2], o[3]);
      *(float4*)(po + 4) = make_float4(o[4], o[5], o[6], o[7]);
    }
  }
}

// ---------------- launch ----------------
extern "C" void kernel_launch(void* const* d_in, const int* in_sizes, int n_in,
                              void* d_out, int out_size, void* d_ws, size_t ws_size,
                              hipStream_t stream) {
  const float* x = (const float*)d_in[0];
  const int* ei = (const int*)d_in[1];
  const float* W1 = (const float*)d_in[2];
  const float* b1 = (const float*)d_in[3];
  const float* W2 = (const float*)d_in[4];
  const float* b2 = (const float*)d_in[5];
  float* out = (float*)d_out;

  const int n = in_sizes[0] / IN_F;   // 50000
  const int e = in_sizes[1] / 2;      // 800000
  const int* e_src = ei;
  const int* e_dst = ei + e;

  uint8_t* ws = (uint8_t*)d_ws;
  size_t off = 0;
  auto carve = [&](size_t bytes) {
    uint8_t* p = ws + off;
    off = (off + bytes + 255) & ~(size_t)255;
    return p;
  };
  short* h1 = (short*)carve((size_t)n * HID * 2);
  short* h2 = (short*)carve((size_t)n * HID * 2);
  short* t2 = (short*)carve((size_t)n * OUTF * 2);
  short* w1t = (short*)carve((size_t)HID * IN_F * 2);
  short* w2t = (short*)carve((size_t)OUTF * HID * 2);
  int* cnt = (int*)carve((size_t)(n + 1) * 4);  // cnt[n] = global alloc counter
  int* rowp = (int*)carve((size_t)(n + 1) * 4);
  int* cursor = (int*)carve((size_t)n * 4);
  float* dinv = (float*)carve((size_t)n * 4);
  int* ssrc = (int*)carve((size_t)e * 4);
  (void)n_in; (void)out_size; (void)ws_size;

  // prep: both weight transposes + zero cnt[n+1] in one launch
  {
    int total = IN_F * HID + HID * OUTF + (n + 1);
    k_prep<<<(total + 255) / 256, 256, 0, stream>>>(W1, w1t, W2, w2t, cnt, n + 1);
  }

  // CSR build
  k_hist<<<(e + 255) / 256, 256, 0, stream>>>(e_dst, cnt, e);
  k_alloc<<<(n + 255) / 256, 256, 0, stream>>>(cnt, rowp, cursor, dinv, &cnt[n], n);
  k_fill<<<(e + 255) / 256, 256, 0, stream>>>(e_src, e_dst, cursor, ssrc, e);

  // layer 1: h1 = dinv .* (x @ W1); h2 = relu(dinv .* (sum + self) + b1)
  {
    dim3 grid((n + 127) / 128, HID / 128);  // (391, 2)
    k_gemm1<<<grid, 256, 0, stream>>>(x, w1t, h1, dinv, n, IN_F);
  }
  k_agg5<HID, true, short><<<(n + 3) / 4, 256, 0, stream>>>(h1, rowp, cnt, ssrc, dinv, b1, h2, n);

  // layer 2: t2 = dinv .* (h2 @ W2); out = dinv .* (sum + self) + b2
  {
    dim3 grid((n + 127) / 128, OUTF / 128);
    k_gemm_a<<<grid, 256, 0, stream>>>(h2, w2t, t2, dinv, n, OUTF, HID);
  }
  k_agg5<OUTF, false, float><<<(n + 3) / 4, 256, 0, stream>>>(t2, rowp, cnt, ssrc, dinv, b2, out, n);
}

// Round 10
// 443.670 us; speedup vs baseline: 1.5904x; 1.0533x over previous
//
#include <hip/hip_runtime.h>
#include <hip/hip_bf16.h>
#include <stdint.h>

#define IN_F 768
#define HID 256
#define OUTF 128

typedef short bf16x8 __attribute__((ext_vector_type(8)));
typedef float f32x4 __attribute__((ext_vector_type(4)));

__device__ inline short f2bf(float f) {
  union { __hip_bfloat16 b; short s; } u;
  u.b = __float2bfloat16(f);
  return u.s;
}
__device__ inline float bf2f(uint32_t bits) {
  union { uint32_t u; float f; } x; x.u = bits << 16; return x.f;
}

// ---------------- prep: zero counters + transpose/convert both weights ----
__global__ void k_prep(const float* __restrict__ W1, short* __restrict__ W1t,
                       const float* __restrict__ W2, short* __restrict__ W2t,
                       int* __restrict__ cnt, int nz) {
  int idx = blockIdx.x * blockDim.x + threadIdx.x;
  const int n1 = IN_F * HID;
  const int n2 = HID * OUTF;
  if (idx < n1) {
    int nn = idx / IN_F, kk = idx - nn * IN_F;
    W1t[idx] = f2bf(W1[kk * HID + nn]);
  } else if (idx < n1 + n2) {
    int j = idx - n1;
    int nn = j / HID, kk = j - nn * HID;
    W2t[j] = f2bf(W2[kk * OUTF + nn]);
  } else {
    int z = idx - n1 - n2;
    if (z < nz) cnt[z] = 0;
  }
}

__global__ void k_hist(const int* __restrict__ dst, int* __restrict__ cnt, int e) {
  int i = blockIdx.x * blockDim.x + threadIdx.x;
  if (i < e) atomicAdd(&cnt[dst[i]], 1);
}

// scan-free CSR row allocation: wave-local shuffle scan + 1 atomic per wave.
__global__ void k_alloc(const int* __restrict__ cnt, int* __restrict__ rowp,
                        int* __restrict__ cursor, float* __restrict__ dinv,
                        int* __restrict__ gtot, int n) {
  int i = blockIdx.x * blockDim.x + threadIdx.x;
  int lane = threadIdx.x & 63;
  int v = (i < n) ? cnt[i] : 0;
  int incl = v;
#pragma unroll
  for (int off = 1; off < 64; off <<= 1) {
    int t = __shfl_up(incl, off);
    if (lane >= off) incl += t;
  }
  int wsum = __shfl(incl, 63);
  int base = 0;
  if (lane == 63) base = atomicAdd(gtot, wsum);
  base = __shfl(base, 63);
  if (i < n) {
    int start = base + incl - v;
    rowp[i] = start;
    cursor[i] = start;
    dinv[i] = rsqrtf((float)(v + 1));  // +1 self-loop
  }
}

__global__ void k_fill(const int* __restrict__ src, const int* __restrict__ dst,
                       int* __restrict__ cursor, int* __restrict__ ssrc, int e) {
  int i = blockIdx.x * blockDim.x + threadIdx.x;
  if (i < e) {
    int d = dst[i];
    int pos = atomicAdd(&cursor[d], 1);
    ssrc[pos] = src[i];
  }
}

// XOR swizzle: slot offset (shorts) into a [rows][32] bf16 tile.
// r9-verified (bank conflicts -> 0, refcheck pass).
__device__ inline int soff(int row, int q) {
  return row * 32 + ((q ^ ((row >> 1) & 3)) << 3);
}

__device__ inline void glds16(const short* g, short* l) {
  __builtin_amdgcn_global_load_lds((const __attribute__((address_space(1))) void*)g,
                                   (__attribute__((address_space(3))) void*)l, 16, 0, 0);
}

// ---------------- GEMM1 v3: 128x256 tile (A read once), 512 thr = 8 waves -
// r8: v1 (256thr) latency-bound at 1.5 blocks/CU (4-8 waves/CU). r9: v2
// raised occupancy but doubled A-traffic + halved per-block intensity ->
// regressed. v3 keeps v1's tile & traffic, doubles in-block waves: every
// occupied CU holds >=8 waves. B staged via async global_load_lds (linear
// dest + inverse-swz source + swz read, rule #21); A reg-staged (f32->bf16
// cvt) with both-sides swz; A prefetch overlaps MFMA.
__global__ __launch_bounds__(512, 4) void k_gemm1(const float* __restrict__ A,
                                                  const short* __restrict__ Bt,
                                                  short* __restrict__ C,
                                                  const float* __restrict__ dinv,
                                                  int M, int K) {
  __shared__ __align__(16) short As[128 * 32];
  __shared__ __align__(16) short Bs[256 * 32];
  const int tid = threadIdx.x;
  const int tile_m = blockIdx.x * 128;
  const int wave = tid >> 6;
  const int lane = tid & 63;
  const int wm = (wave >> 1) * 32;   // 4 row-groups of 32
  const int wn = (wave & 1) * 128;   // 2 col-groups of 128
  const int lrow = lane & 15;
  const int quad = lane >> 4;

  // A staging: thread -> row rA (0..127), col-slot qA (8 f32)
  const int rA = tid >> 2;
  const int qA = tid & 3;
  int grA = tile_m + rA; if (grA >= M) grA = M - 1;
  const float* pA = A + (size_t)grA * K + qA * 8;

  // B staging via glds16: chunks c = tid, tid+512 -> row rB=c>>2 (0..255),
  // slot qB=c&3; LDS dest linear (c*8 shorts); source col pre-swizzled so
  // the swizzled READ returns the natural layout (rule #21).
  const int rB0 = tid >> 2, qB0 = tid & 3;
  const int rB1 = rB0 + 128;
  const int cB0 = (qB0 ^ ((rB0 >> 1) & 3)) * 8;
  const int cB1 = (qB0 ^ ((rB1 >> 1) & 3)) * 8;
  const short* pB0 = Bt + (size_t)rB0 * K + cB0;
  const short* pB1 = Bt + (size_t)rB1 * K + cB1;

  float4 a0[2];
  auto ldA = [&](int k0) {
    a0[0] = *(const float4*)(pA + k0);
    a0[1] = *(const float4*)(pA + k0 + 4);
  };

  f32x4 zero = {0.f, 0.f, 0.f, 0.f};
  f32x4 acc[2][8];
#pragma unroll
  for (int i = 0; i < 2; i++)
#pragma unroll
    for (int j = 0; j < 8; j++) acc[i][j] = zero;

  ldA(0);
  for (int k0 = 0; k0 < K; k0 += 32) {
    glds16(pB0 + k0, &Bs[(size_t)tid * 8]);
    glds16(pB1 + k0, &Bs[(size_t)(tid + 512) * 8]);
    bf16x8 pk;
    pk[0] = f2bf(a0[0].x); pk[1] = f2bf(a0[0].y); pk[2] = f2bf(a0[0].z); pk[3] = f2bf(a0[0].w);
    pk[4] = f2bf(a0[1].x); pk[5] = f2bf(a0[1].y); pk[6] = f2bf(a0[1].z); pk[7] = f2bf(a0[1].w);
    *(bf16x8*)&As[soff(rA, qA)] = pk;
    __builtin_amdgcn_s_waitcnt(0xcf70);  // vmcnt(0): drain glds16
    __syncthreads();

    if (k0 + 32 < K) ldA(k0 + 32);  // next A-tile in flight across MFMA

    bf16x8 af[2], bfr[8];
#pragma unroll
    for (int i = 0; i < 2; i++)
      af[i] = *(const bf16x8*)&As[soff(wm + i * 16 + lrow, quad)];
#pragma unroll
    for (int j = 0; j < 8; j++)
      bfr[j] = *(const bf16x8*)&Bs[soff(wn + j * 16 + lrow, quad)];
#pragma unroll
    for (int i = 0; i < 2; i++)
#pragma unroll
      for (int j = 0; j < 8; j++)
        acc[i][j] = __builtin_amdgcn_mfma_f32_16x16x32_bf16(af[i], bfr[j],
                                                            acc[i][j], 0, 0, 0);
    __syncthreads();
  }

#pragma unroll
  for (int i = 0; i < 2; i++) {
#pragma unroll
    for (int r = 0; r < 4; r++) {
      int grow = tile_m + wm + i * 16 + quad * 4 + r;
      if (grow < M) {
        float dv = dinv[grow];
#pragma unroll
        for (int j = 0; j < 8; j++) {
          int gcol = wn + j * 16 + lrow;
          C[(size_t)grow * HID + gcol] = f2bf(dv * acc[i][j][r]);
        }
      }
    }
  }
}

// ---------------- async MFMA GEMM (m97 structure), bf16 A, dinv epilogue --
__global__ __launch_bounds__(256) void k_gemm_a(const short* __restrict__ A,
                                                const short* __restrict__ Bt,
                                                short* __restrict__ C,
                                                const float* __restrict__ dinv,
                                                int M, int N, int K) {
  __shared__ __align__(16) short As[128 * 32];
  __shared__ __align__(16) short Bs[128 * 32];
  const int tid = threadIdx.x;
  const int tile_m = blockIdx.x * 128;
  const int tile_n = blockIdx.y * 128;
  const int wave = tid >> 6;
  const int lane = tid & 63;
  const int wm = (wave & 1) * 64;
  const int wn = (wave >> 1) * 64;
  const int lrow = lane & 15;
  const int quad = lane >> 4;

  const int c = tid, c2 = tid + 256;
  const int rowA = c >> 2, colA = (c & 3) * 8;
  const int rowA2 = c2 >> 2, colA2 = (c2 & 3) * 8;
  int grA = tile_m + rowA;  if (grA >= M) grA = M - 1;
  int grA2 = tile_m + rowA2; if (grA2 >= M) grA2 = M - 1;
  const short* pA = A + (size_t)grA * K + colA;
  const short* pA2 = A + (size_t)grA2 * K + colA2;
  const short* pB = Bt + (size_t)(tile_n + rowA) * K + colA;
  const short* pB2 = Bt + (size_t)(tile_n + rowA2) * K + colA2;

  f32x4 zero = {0.f, 0.f, 0.f, 0.f};
  f32x4 acc[4][4];
#pragma unroll
  for (int i = 0; i < 4; i++)
#pragma unroll
    for (int j = 0; j < 4; j++) acc[i][j] = zero;

  for (int k0 = 0; k0 < K; k0 += 32) {
    glds16(pA + k0, &As[c * 8]);
    glds16(pA2 + k0, &As[c2 * 8]);
    glds16(pB + k0, &Bs[c * 8]);
    glds16(pB2 + k0, &Bs[c2 * 8]);
    __builtin_amdgcn_s_waitcnt(0xcf70);  // vmcnt(0)
    __syncthreads();

    bf16x8 af[4], bfr[4];
#pragma unroll
    for (int i = 0; i < 4; i++)
      af[i] = *(const bf16x8*)&As[(wm + i * 16 + lrow) * 32 + quad * 8];
#pragma unroll
    for (int j = 0; j < 4; j++)
      bfr[j] = *(const bf16x8*)&Bs[(wn + j * 16 + lrow) * 32 + quad * 8];
#pragma unroll
    for (int i = 0; i < 4; i++)
#pragma unroll
      for (int j = 0; j < 4; j++)
        acc[i][j] = __builtin_amdgcn_mfma_f32_16x16x32_bf16(af[i], bfr[j],
                                                            acc[i][j], 0, 0, 0);
    __syncthreads();
  }

#pragma unroll
  for (int i = 0; i < 4; i++) {
#pragma unroll
    for (int r = 0; r < 4; r++) {
      int grow = tile_m + wm + i * 16 + quad * 4 + r;
      if (grow < M) {
        float dv = dinv[grow];
#pragma unroll
        for (int j = 0; j < 4; j++) {
          int gcol = tile_n + wn + j * 16 + lrow;
          C[(size_t)grow * N + gcol] = f2bf(dv * acc[i][j][r]);
        }
      }
    }
  }
}

// ---------------- CSR aggregation: wave/node, unweighted sum of pre-scaled
// rows. 16 B/lane gathers; 2-deep accumulator unroll.
template <int F, bool RELU, typename OT>
__global__ __launch_bounds__(256) void k_agg5(const short* __restrict__ H,
                                              const int* __restrict__ rowp,
                                              const int* __restrict__ cnt,
                                              const int* __restrict__ ssrc,
                                              const float* __restrict__ dinv,
                                              const float* __restrict__ bias,
                                              OT* __restrict__ out, int n) {
  constexpr int LPE = F / 8;     // lanes per edge-row: 32 (F=256), 16 (F=128)
  constexpr int EPW = 64 / LPE;  // edges per wave-load: 2 or 4
  const int lane = threadIdx.x & 63;
  const int i = blockIdx.x * 4 + (threadIdx.x >> 6);
  if (i >= n) return;
  const int q = lane / LPE;        // edge sub-group
  const int fl = (lane % LPE) * 8; // feat offset (8 feats = 16 B bf16)
  const float di = dinv[i];

  float a[8], b[8];
  auto fmadd = [&](float* ac, uint4 u, float w) {
    ac[0] = fmaf(w, bf2f(u.x & 0xffffu), ac[0]);
    ac[1] = fmaf(w, bf2f(u.x >> 16), ac[1]);
    ac[2] = fmaf(w, bf2f(u.y & 0xffffu), ac[2]);
    ac[3] = fmaf(w, bf2f(u.y >> 16), ac[3]);
    ac[4] = fmaf(w, bf2f(u.z & 0xffffu), ac[4]);
    ac[5] = fmaf(w, bf2f(u.z >> 16), ac[5]);
    ac[6] = fmaf(w, bf2f(u.w & 0xffffu), ac[6]);
    ac[7] = fmaf(w, bf2f(u.w >> 16), ac[7]);
  };

  {  // self term (pre-scaled row), owned by sub-group 0 only
    uint4 u = *(const uint4*)(H + (size_t)i * F + fl);
#pragma unroll
    for (int j = 0; j < 8; j++) { a[j] = 0.f; b[j] = 0.f; }
    fmadd(a, u, (q == 0) ? 1.f : 0.f);
  }

  const int p0 = rowp[i];
  const int deg = cnt[i];
  for (int pb = 0; pb < deg; pb += 64) {
    int m = deg - pb; if (m > 64) m = 64;
    int sl = (lane < m) ? ssrc[p0 + pb + lane] : 0;
    for (int e = 0; e < m; e += 2 * EPW) {
      const int i0 = e + q, i1 = e + EPW + q;
      const int s0 = __shfl(sl, i0);
      const int s1 = __shfl(sl, i1);
      const float w0 = (i0 < m) ? 1.f : 0.f;
      const float w1 = (i1 < m) ? 1.f : 0.f;
      uint4 u0 = *(const uint4*)(H + (size_t)s0 * F + fl);
      uint4 u1 = *(const uint4*)(H + (size_t)s1 * F + fl);
      fmadd(a, u0, w0);
      fmadd(b, u1, w1);
    }
  }
#pragma unroll
  for (int j = 0; j < 8; j++) a[j] += b[j];
#pragma unroll
  for (int mask = LPE; mask < 64; mask <<= 1) {
#pragma unroll
    for (int j = 0; j < 8; j++) a[j] += __shfl_xor(a[j], mask);
  }

  if (q == 0) {
    float o[8];
#pragma unroll
    for (int j = 0; j < 8; j++) {
      o[j] = di * a[j] + bias[fl + j];
      if (RELU) o[j] = fmaxf(o[j], 0.f);
    }
    if constexpr (sizeof(OT) == 2) {
      uint4 pk;
      pk.x = (uint32_t)(uint16_t)f2bf(o[0]) | ((uint32_t)(uint16_t)f2bf(o[1]) << 16);
      pk.y = (uint32_t)(uint16_t)f2bf(o[2]) | ((uint32_t)(uint16_t)f2bf(o[3]) << 16);
      pk.z = (uint32_t)(uint16_t)f2bf(o[4]) | ((uint32_t)(uint16_t)f2bf(o[5]) << 16);
      pk.w = (uint32_t)(uint16_t)f2bf(o[6]) | ((uint32_t)(uint16_t)f2bf(o[7]) << 16);
      *(uint4*)((short*)out + (size_t)i * F + fl) = pk;
    } else {
      float* po = (float*)out + (size_t)i * F + fl;
      *(float4*)po = make_float4(o[0], o[1], o[2], o[3]);
      *(float4*)(po + 4) = make_float4(o[4], o[5], o[6], o[7]);
    }
  }
}

// ---------------- launch ----------------
extern "C" void kernel_launch(void* const* d_in, const int* in_sizes, int n_in,
                              void* d_out, int out_size, void* d_ws, size_t ws_size,
                              hipStream_t stream) {
  const float* x = (const float*)d_in[0];
  const int* ei = (const int*)d_in[1];
  const float* W1 = (const float*)d_in[2];
  const float* b1 = (const float*)d_in[3];
  const float* W2 = (const float*)d_in[4];
  const float* b2 = (const float*)d_in[5];
  float* out = (float*)d_out;

  const int n = in_sizes[0] / IN_F;   // 50000
  const int e = in_sizes[1] / 2;      // 800000
  const int* e_src = ei;
  const int* e_dst = ei + e;

  uint8_t* ws = (uint8_t*)d_ws;
  size_t off = 0;
  auto carve = [&](size_t bytes) {
    uint8_t* p = ws + off;
    off = (off + bytes + 255) & ~(size_t)255;
    return p;
  };
  short* h1 = (short*)carve((size_t)n * HID * 2);
  short* h2 = (short*)carve((size_t)n * HID * 2);
  short* t2 = (short*)carve((size_t)n * OUTF * 2);
  short* w1t = (short*)carve((size_t)HID * IN_F * 2);
  short* w2t = (short*)carve((size_t)OUTF * HID * 2);
  int* cnt = (int*)carve((size_t)(n + 1) * 4);  // cnt[n] = global alloc counter
  int* rowp = (int*)carve((size_t)(n + 1) * 4);
  int* cursor = (int*)carve((size_t)n * 4);
  float* dinv = (float*)carve((size_t)n * 4);
  int* ssrc = (int*)carve((size_t)e * 4);
  (void)n_in; (void)out_size; (void)ws_size;

  // prep: both weight transposes + zero cnt[n+1] in one launch
  {
    int total = IN_F * HID + HID * OUTF + (n + 1);
    k_prep<<<(total + 255) / 256, 256, 0, stream>>>(W1, w1t, W2, w2t, cnt, n + 1);
  }

  // CSR build
  k_hist<<<(e + 255) / 256, 256, 0, stream>>>(e_dst, cnt, e);
  k_alloc<<<(n + 255) / 256, 256, 0, stream>>>(cnt, rowp, cursor, dinv, &cnt[n], n);
  k_fill<<<(e + 255) / 256, 256, 0, stream>>>(e_src, e_dst, cursor, ssrc, e);

  // layer 1: h1 = dinv .* (x @ W1); h2 = relu(dinv .* (sum + self) + b1)
  k_gemm1<<<(n + 127) / 128, 512, 0, stream>>>(x, w1t, h1, dinv, n, IN_F);
  k_agg5<HID, true, short><<<(n + 3) / 4, 256, 0, stream>>>(h1, rowp, cnt, ssrc, dinv, b1, h2, n);

  // layer 2: t2 = dinv .* (h2 @ W2); out = dinv .* (sum + self) + b2
  {
    dim3 grid((n + 127) / 128, OUTF / 128);
    k_gemm_a<<<grid, 256, 0, stream>>>(h2, w2t, t2, dinv, n, OUTF, HID);
  }
  k_agg5<OUTF, false, float><<<(n + 3) / 4, 256, 0, stream>>>(t2, rowp, cnt, ssrc, dinv, b2, out, n);
}